// Round 5
// baseline (837.076 us; speedup 1.0000x reference)
//
#include <hip/hip_runtime.h>
#include <cstddef>

typedef unsigned short u16;
typedef unsigned int   u32;
typedef short  bf16x8 __attribute__((ext_vector_type(8)));
typedef float  f32x4  __attribute__((ext_vector_type(4)));

#define L_SEQ   2048
#define D_MODEL 2048
#define NHEADS  16
#define DHEAD   128
#define NBH     64
#define M_ROWS  8192
#define LOG2E   1.4426950408889634f

__device__ __forceinline__ u16 f2bf(float f) {
  u32 u = __float_as_uint(f);
  u32 r = (u + 0x7FFFu + ((u >> 16) & 1u)) >> 16;   // RNE; inputs finite
  return (u16)r;
}
__device__ __forceinline__ float bf2f(u16 u) {
  return __uint_as_float(((u32)u) << 16);
}
__device__ __forceinline__ void load_lds16(const u16* g, u16* l) {
  __builtin_amdgcn_global_load_lds((const __attribute__((address_space(1))) u32*)g,
                                   (__attribute__((address_space(3))) u32*)l, 16, 0, 0);
}

// ======================= fused fp32 -> bf16 casts + rope table =======================
// y=0: x ; y=1..4: Wq,Wk,Wv,Wo ; y=5: rope cos/sin table (first 512 x-blocks)
__global__ __launch_bounds__(256)
void cast_all(const float* __restrict__ x,
              const float* __restrict__ wq, const float* __restrict__ wk,
              const float* __restrict__ wv, const float* __restrict__ wo,
              u16* __restrict__ xb, u16* __restrict__ wqb, u16* __restrict__ wkb,
              u16* __restrict__ wvb, u16* __restrict__ wob,
              float2* __restrict__ rtab) {
  const int y = blockIdx.y;
  if (y == 5) {
    const int i = blockIdx.x * 256 + threadIdx.x;
    if (i >= L_SEQ * 64) return;
    const int l = i >> 6, p = i & 63;
    const float invf = exp2f(-(float)p * (13.287712379549449f / 64.f));  // 10000^(-p/64)
    float s, c;
    sincosf((float)l * invf, &s, &c);
    rtab[i] = make_float2(c, s);
    return;
  }
  const float* s; u16* d; int n4;
  const int NX4 = M_ROWS * D_MODEL / 4;
  const int W4  = D_MODEL * D_MODEL / 4;
  switch (y) {
    case 0: s = x;  d = xb;  n4 = NX4; break;
    case 1: s = wq; d = wqb; n4 = W4;  break;
    case 2: s = wk; d = wkb; n4 = W4;  break;
    case 3: s = wv; d = wvb; n4 = W4;  break;
    default: s = wo; d = wob; n4 = W4; break;
  }
  int i = blockIdx.x * 256 + threadIdx.x;
  if (i >= n4) return;
  float4 v = ((const float4*)s)[i];
  ushort4 o;
  o.x = f2bf(v.x); o.y = f2bf(v.y); o.z = f2bf(v.z); o.w = f2bf(v.w);
  ((ushort4*)d)[i] = o;
}

// ======================= GEMM core: 128x128 tile, BK=64, bf16 MFMA =======================
__device__ __forceinline__ void gemm_core(const u16* __restrict__ A, const u16* __restrict__ W,
                                          u16* As, u16* Bs, int rBase, int cBase,
                                          f32x4 (&acc)[4][4]) {
  const int tid  = threadIdx.x;
  const int wave = tid >> 6, lane = tid & 63;
  const int quad = lane >> 4, l15 = lane & 15;
  const int wr = wave >> 1, wc = wave & 1;

#pragma unroll
  for (int m = 0; m < 4; ++m)
#pragma unroll
    for (int n = 0; n < 4; ++n) acc[m][n] = (f32x4){0.f, 0.f, 0.f, 0.f};

  for (int kb = 0; kb < D_MODEL; kb += 64) {
    __syncthreads();
#pragma unroll
    for (int i = 0; i < 4; ++i) {
      const int s = (wave * 4 + i) * 64 + lane;
      const int n = s >> 3;
      const int c = (s & 7) ^ (n & 7);
      load_lds16(A + (size_t)(rBase + n) * D_MODEL + kb + c * 8,
                 As + (size_t)(wave * 4 + i) * 512);
      load_lds16(W + (size_t)(cBase + n) * D_MODEL + kb + c * 8,
                 Bs + (size_t)(wave * 4 + i) * 512);
    }
    __syncthreads();
#pragma unroll
    for (int h = 0; h < 2; ++h) {
      bf16x8 af[4], bfr[4];
#pragma unroll
      for (int m = 0; m < 4; ++m) {
        const int row = wr * 64 + m * 16 + l15;
        const int cc = (h * 4 + quad) ^ (row & 7);
        af[m] = *(const bf16x8*)(As + row * 64 + cc * 8);
      }
#pragma unroll
      for (int n = 0; n < 4; ++n) {
        const int row = wc * 64 + n * 16 + l15;
        const int cc = (h * 4 + quad) ^ (row & 7);
        bfr[n] = *(const bf16x8*)(Bs + row * 64 + cc * 8);
      }
#pragma unroll
      for (int m = 0; m < 4; ++m)
#pragma unroll
        for (int n = 0; n < 4; ++n)
          acc[m][n] = __builtin_amdgcn_mfma_f32_16x16x32_bf16(af[m], bfr[n], acc[m][n], 0, 0, 0);
    }
  }
}

// ======================= fused QKV projection + RoPE/sigmoid =======================
// grid (M/128, 48): seg = y>>4 (0:Q 1:K 2:V), head h = y&15.
#define TP 136   // epilogue LDS tile pitch (u16)
__global__ __launch_bounds__(256)
void gemm_qkv(const u16* __restrict__ A,
              const u16* __restrict__ Wq, const u16* __restrict__ Wk, const u16* __restrict__ Wv,
              u16* __restrict__ Qo, u16* __restrict__ Ko, u16* __restrict__ Vt,
              float* __restrict__ qsq, float* __restrict__ ksq,
              const float2* __restrict__ rtab) {
  __shared__ __align__(16) u16 buf[128 * TP];
  u16* As = buf;
  u16* Bs = buf + 8192;

  const int tid  = threadIdx.x;
  const int wave = tid >> 6, lane = tid & 63;
  const int quad = lane >> 4, l15 = lane & 15;
  const int wr = wave >> 1, wc = wave & 1;
  const int rBase = blockIdx.x << 7;
  const int seg = blockIdx.y >> 4;
  const int h   = blockIdx.y & 15;
  const int cBase = h << 7;
  const u16* W = (seg == 0) ? Wq : (seg == 1) ? Wk : Wv;

  f32x4 acc[4][4];
  gemm_core(A, W, As, Bs, rBase, cBase, acc);

  __syncthreads();   // main loop LDS reads done; reuse buf
  if (seg < 2) {
    // tile T[l_loc][p]
#pragma unroll
    for (int m = 0; m < 4; ++m)
#pragma unroll
      for (int n = 0; n < 4; ++n) {
        const int l0 = wr * 64 + m * 16 + quad * 4;
        const int p  = wc * 64 + n * 16 + l15;
#pragma unroll
        for (int r = 0; r < 4; ++r)
          buf[(l0 + r) * TP + p] = f2bf(acc[m][n][r]);
      }
    __syncthreads();

    // RoPE (table) + sigmoid + square-sums, then store.
    const int row = tid >> 1, sel = tid & 1;
    const int p0 = sel * 32;
    const int token = rBase + row;
    const int b = token >> 11, l = token & 2047;
    u16* base = (seg == 0) ? Qo : Ko;
    float* sq = (seg == 0) ? qsq : ksq;
    u16* dst = base + ((size_t)(b * NHEADS + h) * L_SEQ + l) * DHEAD;
    const float4* tb4 = (const float4*)(rtab + (size_t)l * 64 + p0);   // 2 (cos,sin) per float4
    float ss = 0.f;
#pragma unroll
    for (int c4 = 0; c4 < 4; ++c4) {
      const bf16x8 a  = *(const bf16x8*)&buf[row * TP + p0 + c4 * 8];
      const bf16x8 bb = *(const bf16x8*)&buf[row * TP + p0 + c4 * 8 + 64];
      bf16x8 out1, out2;
#pragma unroll
      for (int j2 = 0; j2 < 4; ++j2) {
        const float4 cs2 = tb4[c4 * 4 + j2];
#pragma unroll
        for (int e = 0; e < 2; ++e) {
          const int j = j2 * 2 + e;
          const float cv = e ? cs2.z : cs2.x;
          const float sv = e ? cs2.w : cs2.y;
          const float v1 = bf2f((u16)a[j]);
          const float v2 = bf2f((u16)bb[j]);
          float o1 = v1 * cv - v2 * sv;
          float o2 = v2 * cv + v1 * sv;
          o1 = 1.f / (1.f + __expf(-o1));
          o2 = 1.f / (1.f + __expf(-o2));
          const u16 b1 = f2bf(o1), b2 = f2bf(o2);
          out1[j] = (short)b1; out2[j] = (short)b2;
          const float r1 = bf2f(b1), r2 = bf2f(b2);
          ss += r1 * r1 + r2 * r2;
        }
      }
      *(bf16x8*)(dst + p0 + c4 * 8) = out1;
      *(bf16x8*)(dst + p0 + 64 + c4 * 8) = out2;
    }
    ss += __shfl_xor(ss, 1, 64);
    if (sel == 0) sq[(size_t)(b * NHEADS + h) * L_SEQ + l] = ss;
  } else {
    // V: T[p_loc][l_loc], b64-packed
#pragma unroll
    for (int m = 0; m < 4; ++m)
#pragma unroll
      for (int n = 0; n < 4; ++n) {
        const int l0 = wr * 64 + m * 16 + quad * 4;
        const int p  = wc * 64 + n * 16 + l15;
        uint2 pk;
        pk.x = (u32)f2bf(acc[m][n][0]) | ((u32)f2bf(acc[m][n][1]) << 16);
        pk.y = (u32)f2bf(acc[m][n][2]) | ((u32)f2bf(acc[m][n][3]) << 16);
        *(uint2*)&buf[p * TP + l0] = pk;
      }
    __syncthreads();
    const int row = tid >> 1, hf = tid & 1;
    const u16* src = buf + row * TP + hf * 64;
    const int b = rBase >> 11, l0 = (rBase & 2047) + hf * 64;
    u16* dst = Vt + ((size_t)(b * NHEADS + h) * DHEAD + row) * L_SEQ + l0;
#pragma unroll
    for (int c = 0; c < 8; ++c)
      *(bf16x8*)(dst + c * 8) = *(const bf16x8*)(src + c * 8);
  }
}

// ======================= output projection: C = A * Wo^T (f32 out) =======================
__global__ __launch_bounds__(256)
void gemm_out(const u16* __restrict__ A, const u16* __restrict__ W, float* __restrict__ C) {
  __shared__ __align__(16) u16 As[128 * 64];
  __shared__ __align__(16) u16 Bs[128 * 64];
  const int tid  = threadIdx.x;
  const int wave = tid >> 6, lane = tid & 63;
  const int quad = lane >> 4, l15 = lane & 15;
  const int wr = wave >> 1, wc = wave & 1;
  const int rBase = blockIdx.x << 7;
  const int cBase = blockIdx.y << 7;

  f32x4 acc[4][4];
  gemm_core(A, W, As, Bs, rBase, cBase, acc);

#pragma unroll
  for (int m = 0; m < 4; ++m)
#pragma unroll
    for (int n = 0; n < 4; ++n) {
      const int row0 = rBase + wr * 64 + m * 16 + quad * 4;
      const int col  = cBase + wc * 64 + n * 16 + l15;
#pragma unroll
      for (int r = 0; r < 4; ++r)
        C[(size_t)(row0 + r) * D_MODEL + col] = acc[m][n][r];
    }
}

// ======================= MFMA flash attention, BQ=128, fixed max=0 =======================
__global__ __launch_bounds__(256)
void attn_mfma(const u16* __restrict__ Q, const u16* __restrict__ K, const u16* __restrict__ Vg,
               const float* __restrict__ qsq_g, const float* __restrict__ ksq_g,
               const float* __restrict__ taup, u16* __restrict__ Ob) {
  __shared__ __align__(16) u16 Ks[64 * 128];   // [key][d], chunk c^(key&15)
  __shared__ __align__(16) u16 Vs[128 * 64];   // [vdim][key], chunk c^(vdim&7)
  __shared__ __align__(16) u16 Ps[4][32 * 72]; // per-wave P [q][key] bf16, pitch 72
  __shared__ float ksqs[64];

  const int qt = (int)gridDim.x - 1 - (int)blockIdx.x;   // big tiles first
  const int bh = blockIdx.y;
  const int tid = threadIdx.x;
  const int wave = tid >> 6, lane = tid & 63;
  const int quad = lane >> 4, l15 = lane & 15;
  const int qBase = qt * 128;
  const int mrow = quad * 4;

  bf16x8 aq[2][4];
#pragma unroll
  for (int mt = 0; mt < 2; ++mt) {
    const u16* Qrow = Q + ((size_t)bh * L_SEQ + qBase + wave * 32 + mt * 16 + l15) * DHEAD;
#pragma unroll
    for (int kb = 0; kb < 4; ++kb) aq[mt][kb] = *(const bf16x8*)(Qrow + kb * 32 + quad * 8);
  }

  float tau = log1pf(expf(*taup));
  tau = fminf(fmaxf(tau, 0.1f), 10.f);
  const float lt = LOG2E / tau;
  const float c2 = 2.f * lt;

  float qh[2][4];
#pragma unroll
  for (int mt = 0; mt < 2; ++mt)
#pragma unroll
    for (int r = 0; r < 4; ++r)
      qh[mt][r] = qsq_g[(size_t)bh * L_SEQ + qBase + wave * 32 + mt * 16 + mrow + r] * lt;

  float lst[2][4] = {{0.f, 0.f, 0.f, 0.f}, {0.f, 0.f, 0.f, 0.f}};
  f32x4 oacc[2][8];
#pragma unroll
  for (int mt = 0; mt < 2; ++mt)
#pragma unroll
    for (int i = 0; i < 8; ++i) oacc[mt][i] = (f32x4){0.f, 0.f, 0.f, 0.f};

  const int ktmax = 2 * qt + 1;
  for (int kt = 0; kt <= ktmax; ++kt) {
    __syncthreads();
    const u16* Ktile = K + ((size_t)bh * L_SEQ + kt * 64) * DHEAD;
#pragma unroll
    for (int i = 0; i < 4; ++i) {
      const int s = (wave * 4 + i) * 64 + lane;
      const int n = s >> 4;
      const int c = (s & 15) ^ (n & 15);
      load_lds16(Ktile + n * DHEAD + c * 8, Ks + (size_t)(wave * 4 + i) * 512);
    }
    const u16* Vtile = Vg + (size_t)bh * DHEAD * L_SEQ + kt * 64;
#pragma unroll
    for (int i = 0; i < 4; ++i) {
      const int s = (wave * 4 + i) * 64 + lane;
      const int n = s >> 3;
      const int c = (s & 7) ^ (n & 7);
      load_lds16(Vtile + (size_t)n * L_SEQ + c * 8, Vs + (size_t)(wave * 4 + i) * 512);
    }
    if (tid < 64) ksqs[tid] = ksq_g[(size_t)bh * L_SEQ + kt * 64 + tid] * lt;
    __syncthreads();

    // ---- S = Q K^T ; K B-frags loaded ONCE, shared across both m-tiles ----
    f32x4 sfr[2][4];
#pragma unroll
    for (int nt = 0; nt < 4; ++nt) {
      f32x4 c0 = (f32x4){0.f, 0.f, 0.f, 0.f};
      f32x4 c1 = (f32x4){0.f, 0.f, 0.f, 0.f};
      const int brow = nt * 16 + l15;
#pragma unroll
      for (int kb = 0; kb < 4; ++kb) {
        const int cc = (kb * 4 + quad) ^ l15;
        const bf16x8 bf = *(const bf16x8*)(Ks + brow * 128 + cc * 8);
        c0 = __builtin_amdgcn_mfma_f32_16x16x32_bf16(aq[0][kb], bf, c0, 0, 0, 0);
        c1 = __builtin_amdgcn_mfma_f32_16x16x32_bf16(aq[1][kb], bf, c1, 0, 0, 0);
      }
      sfr[0][nt] = c0;
      sfr[1][nt] = c1;
    }

    // ---- p = exp2(qk*c2 - qh - kh), accumulate l, pack P (RTZ bf16) ----
    u16* Pw = &Ps[wave][0];
    const bool diag = (kt >= 2 * qt);
#pragma unroll
    for (int mt = 0; mt < 2; ++mt) {
      const int qg0m = qBase + wave * 32 + mt * 16 + mrow;
#pragma unroll
      for (int nt = 0; nt < 4; ++nt) {
        const float kh = ksqs[nt * 16 + l15];
        const int kg = kt * 64 + nt * 16 + l15;
#pragma unroll
        for (int r = 0; r < 4; ++r) {
          float p = exp2f(sfr[mt][nt][r] * c2 - (qh[mt][r] + kh));
          if (diag && kg > qg0m + r) p = 0.f;
          const u32 u = __float_as_uint(p);
          lst[mt][r] += __uint_as_float(u & 0xFFFF0000u);
          Pw[(mt * 16 + mrow + r) * 72 + nt * 16 + l15] = (u16)(u >> 16);
        }
      }
    }
    __asm__ __volatile__("s_waitcnt lgkmcnt(0)" ::: "memory");
    bf16x8 pf[2][2];
#pragma unroll
    for (int mt = 0; mt < 2; ++mt)
#pragma unroll
      for (int kb = 0; kb < 2; ++kb)
        pf[mt][kb] = *(const bf16x8*)(Pw + (mt * 16 + l15) * 72 + kb * 32 + quad * 8);

    // ---- O += P V (V B-frags shared across both m-tiles) ----
#pragma unroll
    for (int ot = 0; ot < 8; ++ot) {
#pragma unroll
      for (int kb = 0; kb < 2; ++kb) {
        const int cc = (kb * 4 + quad) ^ (l15 & 7);
        const bf16x8 vf = *(const bf16x8*)(Vs + (ot * 16 + l15) * 64 + cc * 8);
#pragma unroll
        for (int mt = 0; mt < 2; ++mt)
          oacc[mt][ot] = __builtin_amdgcn_mfma_f32_16x16x32_bf16(pf[mt][kb], vf, oacc[mt][ot], 0, 0, 0);
      }
    }
  }

  // ---- final l reduction across the 16 key-lanes, write O ----
#pragma unroll
  for (int off = 1; off < 16; off <<= 1)
#pragma unroll
    for (int mt = 0; mt < 2; ++mt)
#pragma unroll
      for (int r = 0; r < 4; ++r) lst[mt][r] += __shfl_xor(lst[mt][r], off, 64);

  const int b = bh >> 4, hh = bh & 15;
#pragma unroll
  for (int mt = 0; mt < 2; ++mt)
#pragma unroll
    for (int r = 0; r < 4; ++r) {
      const float invl = 1.f / lst[mt][r];
      const int qg = qBase + wave * 32 + mt * 16 + mrow + r;
      u16* dst = Ob + ((size_t)(b * L_SEQ + qg)) * D_MODEL + hh * DHEAD;
#pragma unroll
      for (int ot = 0; ot < 8; ++ot)
        dst[ot * 16 + l15] = f2bf(oacc[mt][ot][r] * invl);
    }
}

// ======================= launch =======================
extern "C" void kernel_launch(void* const* d_in, const int* in_sizes, int n_in,
                              void* d_out, int out_size, void* d_ws, size_t ws_size,
                              hipStream_t stream) {
  const float* x     = (const float*)d_in[0];
  const float* Wq    = (const float*)d_in[1];
  const float* Wk    = (const float*)d_in[2];
  const float* Wv    = (const float*)d_in[3];
  const float* Wo    = (const float*)d_in[4];
  const float* tau_p = (const float*)d_in[5];

  const size_t NX = (size_t)M_ROWS * D_MODEL;
  const size_t NW = (size_t)D_MODEL * D_MODEL;
  u16* xb  = (u16*)d_ws;                  // aliased as Obuf after projections
  u16* Wqb = xb  + NX;
  u16* Wkb = Wqb + NW;
  u16* Wvb = Wkb + NW;
  u16* Wob = Wvb + NW;
  u16* Qb  = Wob + NW;
  u16* Kb  = Qb + NX;
  u16* Vtb = Kb + NX;                     // V^T (B,H,d,L)
  float* qsq = (float*)(Vtb + NX);
  float* ksq = qsq + (size_t)NBH * L_SEQ;
  float2* rtab = (float2*)(ksq + (size_t)NBH * L_SEQ);   // (L,64) cos/sin pairs
  u16* Obuf = xb;

  cast_all<<<dim3((int)(NX / 4 / 256), 6), 256, 0, stream>>>(
      x, Wq, Wk, Wv, Wo, xb, Wqb, Wkb, Wvb, Wob, rtab);

  gemm_qkv<<<dim3(M_ROWS / 128, 48), 256, 0, stream>>>(
      xb, Wqb, Wkb, Wvb, Qb, Kb, Vtb, qsq, ksq, rtab);

  attn_mfma<<<dim3(L_SEQ / 128, NBH), 256, 0, stream>>>(Qb, Kb, Vtb, qsq, ksq, tau_p, Obuf);

  gemm_out<<<dim3(M_ROWS / 128, D_MODEL / 128), 256, 0, stream>>>(Obuf, Wob, (float*)d_out);
}